// Round 1
// baseline (25.843 us; speedup 1.0000x reference)
//
#include <hip/hip_runtime.h>
#include <stdint.h>

#define K_DIM 4096
#define KW 1024          // K/4 packed words per m-row
#define M_DIM 11008
#define B_DIM 16
#define GROUP_ROWS 2752  // M / 4 groups
#define CHUNK_W 256      // packed words per b-row per chunk
#define NCHUNK 4

// spread low byte p (4x 2-bit fields) into 4 bytes of an int32: {p&3, (p>>2)&3, (p>>4)&3, (p>>6)&3}
__device__ __forceinline__ int spread2(int p) {
    int t = p | (p << 12);
    int r1 = t & 0x00030003;
    int r2 = (t >> 2) & 0x00030003;
    return r1 | (r2 << 8);
}

__device__ __forceinline__ int dot4(int a, int b, int c) {
    return __builtin_amdgcn_sdot4(a, b, c, false);
}

// ---------------- kernel 1: per-row activation quantization ----------------
__global__ __launch_bounds__(256) void quant_k(const float* __restrict__ in,
                                               int* __restrict__ qg,
                                               int* __restrict__ sumq,
                                               float* __restrict__ invs) {
    const int b = blockIdx.x;
    const int t = threadIdx.x;
    const int lane = t & 63, wid = t >> 6;

    const float4* row = (const float4*)(in + (size_t)b * K_DIM);
    float4 v[4];
#pragma unroll
    for (int i = 0; i < 4; ++i) v[i] = row[t * 4 + i];

    float mx = 0.f;
#pragma unroll
    for (int i = 0; i < 4; ++i) {
        mx = fmaxf(mx, fabsf(v[i].x)); mx = fmaxf(mx, fabsf(v[i].y));
        mx = fmaxf(mx, fabsf(v[i].z)); mx = fmaxf(mx, fabsf(v[i].w));
    }
#pragma unroll
    for (int s = 1; s < 64; s <<= 1) mx = fmaxf(mx, __shfl_xor(mx, s, 64));

    __shared__ float wmax[4];
    __shared__ int wsum[4];
    if (lane == 0) wmax[wid] = mx;
    __syncthreads();
    const float bm = fmaxf(fmaxf(wmax[0], wmax[1]), fmaxf(wmax[2], wmax[3]));
    const float sc = 127.f / fmaxf(bm, 1e-5f);

    int ss = 0;
    int pk[4];
#pragma unroll
    for (int i = 0; i < 4; ++i) {
        float xs[4] = {v[i].x, v[i].y, v[i].z, v[i].w};
        int w = 0;
#pragma unroll
        for (int j = 0; j < 4; ++j) {
            int q = (int)rintf(xs[j] * sc);           // round-half-even, matches jnp.round
            q = q > 127 ? 127 : (q < -128 ? -128 : q);
            ss += q;
            w |= (q & 255) << (8 * j);
        }
        pk[i] = w;
    }
    // chunked layout: qg[chunk][b][256 words]; thread t owns words kp = 4t..4t+3 (one chunk)
    int4* dst = (int4*)(qg + (t >> 6) * (B_DIM * CHUNK_W) + b * CHUNK_W + (t & 63) * 4);
    *dst = *(int4*)pk;

#pragma unroll
    for (int s = 1; s < 64; s <<= 1) ss += __shfl_xor(ss, s, 64);
    if (lane == 0) wsum[wid] = ss;
    __syncthreads();
    if (t == 0) {
        sumq[b] = wsum[0] + wsum[1] + wsum[2] + wsum[3];
        invs[b] = fmaxf(bm, 1e-5f) / 127.f;
    }
}

// ---------------- kernel 2: ternary GEMM via sdot4 ----------------
// block = 256 threads = 4 waves; each wave owns 4 m-rows; block owns 16 m-rows.
__global__ __launch_bounds__(256) void gemm_k(const int* __restrict__ wp,
                                              const int* __restrict__ qg,
                                              const int* __restrict__ sumq,
                                              const float* __restrict__ invs,
                                              const float* __restrict__ wscale,
                                              float* __restrict__ out) {
    __shared__ int qs[B_DIM * CHUNK_W];  // 16 KB: current k-chunk of q, [b][256]
    const int t = threadIdx.x;
    const int lane = t & 63, wid = t >> 6;
    const int m0 = blockIdx.x * 16 + wid * 4;

    int acc[64];
#pragma unroll
    for (int i = 0; i < 64; ++i) acc[i] = 0;

    for (int c = 0; c < NCHUNK; ++c) {
        if (c) __syncthreads();
        // stage 16 KB chunk: linear copy, coalesced both sides
#pragma unroll
        for (int i = 0; i < 4; ++i) {
            int w = i * 1024 + t * 4;
            *(int4*)(qs + w) = *(const int4*)(qg + c * (B_DIM * CHUNK_W) + w);
        }
        __syncthreads();

        // weights: 4 m-rows, this lane's 4 words (16 k) each, spread to sdot operands
        int wsp[4][4];
#pragma unroll
        for (int m = 0; m < 4; ++m) {
            int4 wr = *(const int4*)(wp + (size_t)(m0 + m) * KW + c * CHUNK_W + lane * 4);
            wsp[m][0] = spread2(wr.x); wsp[m][1] = spread2(wr.y);
            wsp[m][2] = spread2(wr.z); wsp[m][3] = spread2(wr.w);
        }
#pragma unroll
        for (int bg = 0; bg < 4; ++bg) {
            int4 q[4];
#pragma unroll
            for (int i = 0; i < 4; ++i)
                q[i] = *(const int4*)(qs + (bg * 4 + i) * CHUNK_W + lane * 4);
#pragma unroll
            for (int i = 0; i < 4; ++i) {
                const int bi = (bg * 4 + i) * 4;
#pragma unroll
                for (int m = 0; m < 4; ++m) {
                    acc[bi + m] = dot4(q[i].x, wsp[m][0], acc[bi + m]);
                    acc[bi + m] = dot4(q[i].y, wsp[m][1], acc[bi + m]);
                    acc[bi + m] = dot4(q[i].z, wsp[m][2], acc[bi + m]);
                    acc[bi + m] = dot4(q[i].w, wsp[m][3], acc[bi + m]);
                }
            }
        }
    }

    // butterfly halving reduction: 64 accs over 64 lanes -> 1 acc/lane (63 shuffles)
#define RSTAGE(S, N)                                           \
    {                                                          \
        const bool up = (lane & S) != 0;                       \
        _Pragma("unroll") for (int i = 0; i < N; ++i) {        \
            int snd = up ? acc[i] : acc[i + N];                \
            int kp  = up ? acc[i + N] : acc[i];                \
            acc[i] = kp + __shfl_xor(snd, S, 64);              \
        }                                                      \
    }
    RSTAGE(1, 32) RSTAGE(2, 16) RSTAGE(4, 8) RSTAGE(8, 4) RSTAGE(16, 2) RSTAGE(32, 1)
#undef RSTAGE

    // lane l ends holding acc index a = bitrev6(l); a = b*4 + msub
    const int a = ((lane & 1) << 5) | ((lane & 2) << 3) | ((lane & 4) << 1) |
                  ((lane & 8) >> 1) | ((lane & 16) >> 3) | ((lane & 32) >> 5);
    const int b = a >> 2, ms = a & 3;
    const int mr = m0 + ms;
    const float val = (float)(acc[0] - sumq[b]) * invs[b] * wscale[mr / GROUP_ROWS];
    out[(size_t)b * M_DIM + mr] = val;
}

extern "C" void kernel_launch(void* const* d_in, const int* in_sizes, int n_in,
                              void* d_out, int out_size, void* d_ws, size_t ws_size,
                              hipStream_t stream) {
    const float* inp    = (const float*)d_in[0];
    const int*   wp     = (const int*)d_in[1];
    const float* wscale = (const float*)d_in[2];
    float* out = (float*)d_out;

    int*   qg   = (int*)d_ws;                 // 16384 words = 64 KB
    int*   sumq = qg + B_DIM * KW;            // 16 ints
    float* invs = (float*)(sumq + B_DIM);     // 16 floats

    quant_k<<<dim3(B_DIM), dim3(256), 0, stream>>>(inp, qg, sumq, invs);
    gemm_k<<<dim3(M_DIM / 16), dim3(256), 0, stream>>>(wp, qg, sumq, invs, wscale, out);
}